// Round 1
// 430.094 us; speedup vs baseline: 1.0286x; 1.0286x over previous
//
#include <hip/hip_runtime.h>
#include <math.h>

// CSCR: B=32, C=256, H=W=56 (HW=3136). Output = concat(rgb_out, ir_out).
// Dual-dtype (bf16/fp32) runtime-detected. Pipeline (4 kernels, was 6):
//  k_sa     : per-(b,hw) channel mean+max both streams -> sigmoid -> sa32.
//             Detection folded in (per-block, redundant but free from L2);
//             block(0,0) publishes flag + zeroes nmx. 16 B/lane float4 loads,
//             4 hw-positions per thread.
//  k_sim    : per-(b,c) plane dot(sa,x) & sum(x^2), fp64 accum, 16 B/lane.
//  k_sort   : stable ascending rank-sort of 256 sims per (stream,b) +
//             positive count -> atomicMax into nmx (absorbs old k_nmax).
//  k_gather : sorted-channel gather w/ insertion * sa_sig; 16 B/lane.

#define CDIM   256
#define HWDIM  3136
#define CHW    (CDIM * HWDIM)        /* 802816 */
#define PAIRS  1568                  /* HWDIM/2 */
#define QUADS  784                   /* HWDIM/4 */

typedef unsigned short u16;
typedef unsigned int   u32;

__device__ __forceinline__ float bf2f(u32 u) { return __uint_as_float(u << 16); }
__device__ __forceinline__ u16  f2bf(float f) {
    u32 x = __float_as_uint(f);
    return (u16)((x + 0x7FFFu + ((x >> 16) & 1u)) >> 16);   // RNE
}
__device__ __forceinline__ u32 pack2(u32 u, float s0, float s1) {
    float a0 = __uint_as_float(u << 16);
    float a1 = __uint_as_float(u & 0xFFFF0000u);
    u32 lo = f2bf(a0 * s0), hi = f2bf(a1 * s1);
    return lo | (hi << 16);
}
__device__ __forceinline__ u32 maxpack2(u32 u, u32 w, float s0, float s1) {
    float a0 = __uint_as_float(u << 16), a1 = __uint_as_float(u & 0xFFFF0000u);
    float b0 = __uint_as_float(w << 16), b1 = __uint_as_float(w & 0xFFFF0000u);
    u32 lo = f2bf(fmaxf(a0, b0) * s0), hi = f2bf(fmaxf(a1, b1) * s1);
    return lo | (hi << 16);
}

// ---- k_sa: grid (13, 32), block 256 = 4 channel-groups x 64 quad-lanes.
// Each thread covers 4 consecutive hw positions (float4 / 2xu32 loads). ----
__global__ __launch_bounds__(256) void k_sa(const void* __restrict__ rgb_,
                                            const void* __restrict__ ir_,
                                            int* __restrict__ flg,
                                            float* __restrict__ sa32,
                                            int* __restrict__ nmx) {
    // -- per-block dtype detection (first 16 KB of rgb, L2-broadcast cheap) --
    __shared__ int s_det;
    if (threadIdx.x == 0) s_det = 0;
    __syncthreads();
    {
        const u16* r16 = (const u16*)rgb_;
        int w = 0;
        for (int i = threadIdx.x; i < 8192; i += 256) {
            u16 u = r16[i];
            int e = (u >> 7) & 0xFF;
            float v = bf2f((u32)u);
            if (e == 0xFF || fabsf(v) > 1e3f) w++;
        }
        atomicAdd(&s_det, w);
    }
    __syncthreads();
    int md = (s_det > 256) ? 1 : 0;   // 0=bf16 1=fp32
    if (blockIdx.x == 0 && blockIdx.y == 0 && threadIdx.x == 0) {
        flg[0] = md;
        nmx[0] = 0; nmx[1] = 0;       // zero for k_sort's atomicMax
    }

    int b  = blockIdx.y;
    int g  = threadIdx.x >> 6;                       // channel group 0..3
    int ql = blockIdx.x * 64 + (threadIdx.x & 63);   // quad index
    bool act = ql < QUADS;

    double s0 = 0.0, s1 = 0.0, s2 = 0.0, s3 = 0.0;   // rgb+ir sums per pos
    float m0r = -INFINITY, m1r = -INFINITY, m2r = -INFINITY, m3r = -INFINITY;
    float m0i = -INFINITY, m1i = -INFINITY, m2i = -INFINITY, m3i = -INFINITY;

    if (act) {
        if (md == 1) {
            const float4* R = (const float4*)rgb_;
            const float4* I = (const float4*)ir_;
            size_t bq = (size_t)b * (CHW / 4) + ql;
            #pragma unroll 2
            for (int c = g; c < CDIM; c += 4) {
                float4 r = R[bq + (size_t)c * QUADS];
                float4 i = I[bq + (size_t)c * QUADS];
                s0 += (double)r.x + (double)i.x;
                s1 += (double)r.y + (double)i.y;
                s2 += (double)r.z + (double)i.z;
                s3 += (double)r.w + (double)i.w;
                m0r = fmaxf(m0r, r.x); m1r = fmaxf(m1r, r.y);
                m2r = fmaxf(m2r, r.z); m3r = fmaxf(m3r, r.w);
                m0i = fmaxf(m0i, i.x); m1i = fmaxf(m1i, i.y);
                m2i = fmaxf(m2i, i.z); m3i = fmaxf(m3i, i.w);
            }
        } else {
            const u32* R = (const u32*)rgb_;
            const u32* I = (const u32*)ir_;
            size_t bw = (size_t)b * (CHW / 2) + 2 * (size_t)ql;
            #pragma unroll 2
            for (int c = g; c < CDIM; c += 4) {
                size_t o = bw + (size_t)c * PAIRS;
                u32 wr0 = R[o], wr1 = R[o + 1];
                u32 wi0 = I[o], wi1 = I[o + 1];
                float r0 = bf2f(wr0 & 0xFFFFu), r1 = bf2f(wr0 >> 16);
                float r2 = bf2f(wr1 & 0xFFFFu), r3 = bf2f(wr1 >> 16);
                float i0 = bf2f(wi0 & 0xFFFFu), i1 = bf2f(wi0 >> 16);
                float i2 = bf2f(wi1 & 0xFFFFu), i3 = bf2f(wi1 >> 16);
                s0 += (double)r0 + (double)i0;
                s1 += (double)r1 + (double)i1;
                s2 += (double)r2 + (double)i2;
                s3 += (double)r3 + (double)i3;
                m0r = fmaxf(m0r, r0); m1r = fmaxf(m1r, r1);
                m2r = fmaxf(m2r, r2); m3r = fmaxf(m3r, r3);
                m0i = fmaxf(m0i, i0); m1i = fmaxf(m1i, i1);
                m2i = fmaxf(m2i, i2); m3i = fmaxf(m3i, i3);
            }
        }
    }

    __shared__ double shs[4][256];
    __shared__ float  shr[4][256];
    __shared__ float  shi[4][256];
    int t = threadIdx.x;
    shs[0][t] = s0; shs[1][t] = s1; shs[2][t] = s2; shs[3][t] = s3;
    shr[0][t] = m0r; shr[1][t] = m1r; shr[2][t] = m2r; shr[3][t] = m3r;
    shi[0][t] = m0i; shi[1][t] = m1i; shi[2][t] = m2i; shi[3][t] = m3i;
    __syncthreads();
    if (g == 0 && act) {
        #pragma unroll
        for (int k = 1; k < 4; ++k) {
            int t2 = t + 64 * k;
            s0 += shs[0][t2]; s1 += shs[1][t2];
            s2 += shs[2][t2]; s3 += shs[3][t2];
            m0r = fmaxf(m0r, shr[0][t2]); m1r = fmaxf(m1r, shr[1][t2]);
            m2r = fmaxf(m2r, shr[2][t2]); m3r = fmaxf(m3r, shr[3][t2]);
            m0i = fmaxf(m0i, shi[0][t2]); m1i = fmaxf(m1i, shi[1][t2]);
            m2i = fmaxf(m2i, shi[2][t2]); m3i = fmaxf(m3i, shi[3][t2]);
        }
        double sa0 = fmax(s0 * (1.0 / 256.0), (double)m0r + (double)m0i);
        double sa1 = fmax(s1 * (1.0 / 256.0), (double)m1r + (double)m1i);
        double sa2 = fmax(s2 * (1.0 / 256.0), (double)m2r + (double)m2i);
        double sa3 = fmax(s3 * (1.0 / 256.0), (double)m3r + (double)m3i);
        float4 ov;
        ov.x = (float)(1.0 / (1.0 + exp(-sa0)));
        ov.y = (float)(1.0 / (1.0 + exp(-sa1)));
        ov.z = (float)(1.0 / (1.0 + exp(-sa2)));
        ov.w = (float)(1.0 / (1.0 + exp(-sa3)));
        *(float4*)&sa32[(size_t)b * HWDIM + 4 * (size_t)ql] = ov;
    }
}

// ---- k_sim: 4 planes/block (same batch), sa staged in LDS (12.25 KB) ----
__global__ __launch_bounds__(256) void k_sim(const void* __restrict__ rgb_,
                                             const void* __restrict__ ir_,
                                             const int* __restrict__ flg,
                                             const float* __restrict__ sa32,
                                             double* __restrict__ sims) {
    __shared__ float s_sa[HWDIM];
    int p0 = blockIdx.x * 4;
    int b  = (p0 >> 8) & 31;
    {
        const float4* src = (const float4*)(sa32 + (size_t)b * HWDIM);
        float4* dst = (float4*)s_sa;
        for (int i = threadIdx.x; i < QUADS; i += 256) dst[i] = src[i];
    }
    __syncthreads();

    int wid = threadIdx.x >> 6, lane = threadIdx.x & 63;
    int p = p0 + wid;
    int stream = p >> 13;
    int md = flg[0];
    int plane = p & 8191;                 // b*256 + c
    const float4* sv = (const float4*)s_sa;

    double ss = 0.0, dot = 0.0;
    if (md == 1) {
        const float4* x = (const float4*)(stream ? ir_ : rgb_) + (size_t)plane * QUADS;
        #pragma unroll 2
        for (int j = lane; j < QUADS; j += 64) {
            float4 v = x[j];
            float4 s = sv[j];
            ss  = fma((double)v.x, (double)v.x,
                  fma((double)v.y, (double)v.y,
                  fma((double)v.z, (double)v.z,
                  fma((double)v.w, (double)v.w, ss))));
            dot = fma((double)s.x, (double)v.x,
                  fma((double)s.y, (double)v.y,
                  fma((double)s.z, (double)v.z,
                  fma((double)s.w, (double)v.w, dot))));
        }
    } else {
        const u32* x = (const u32*)(stream ? ir_ : rgb_) + (size_t)plane * PAIRS;
        #pragma unroll 2
        for (int j = lane; j < QUADS; j += 64) {
            u32 w0 = x[2 * j], w1 = x[2 * j + 1];
            double v0 = (double)bf2f(w0 & 0xFFFFu), v1 = (double)bf2f(w0 >> 16);
            double v2 = (double)bf2f(w1 & 0xFFFFu), v3 = (double)bf2f(w1 >> 16);
            float4 s = sv[j];
            ss  = fma(v0, v0, fma(v1, v1, fma(v2, v2, fma(v3, v3, ss))));
            dot = fma((double)s.x, v0, fma((double)s.y, v1,
                  fma((double)s.z, v2, fma((double)s.w, v3, dot))));
        }
    }
    #pragma unroll
    for (int off = 32; off >= 1; off >>= 1) {
        ss  += __shfl_xor(ss,  off, 64);
        dot += __shfl_xor(dot, off, 64);
    }
    if (lane == 0) {
        double nrm = sqrt(ss);
        if (nrm < 1e-12) nrm = 1e-12;
        sims[p] = dot / nrm;
    }
}

// ---- k_sort: stable ascending argsort + positive count -> atomicMax nmx ----
__global__ __launch_bounds__(256) void k_sort(const double* __restrict__ sims,
                                              int* __restrict__ ord,
                                              int* __restrict__ nmx) {
    __shared__ double s[256];
    __shared__ int csum;
    int sb = blockIdx.x;
    int c  = threadIdx.x;
    double v = sims[sb * 256 + c];
    if (isnan(v)) v = -INFINITY;        // keep ranks a permutation, always
    s[c] = v;
    if (c == 0) csum = 0;
    __syncthreads();
    int rank = 0;
    #pragma unroll 8
    for (int j = 0; j < 256; ++j) {
        double u = s[j];
        rank += (u < v) || (u == v && j < c);
    }
    ord[sb * 256 + rank] = c;
    unsigned long long m = __ballot(v > 0.0);
    if ((c & 63) == 0) atomicAdd(&csum, (int)__popcll(m));
    __syncthreads();
    if (c == 0) atomicMax(&nmx[sb >> 5], csum);   // nmx pre-zeroed by k_sa
}

// ---- k_gather: grid 16384 = stream*8192 + b*256 + c_out, block 256 ----
__global__ __launch_bounds__(256) void k_gather(const void* __restrict__ rgb_,
                                                const void* __restrict__ ir_,
                                                const int* __restrict__ flg,
                                                const float* __restrict__ sa32,
                                                const int* __restrict__ ord,
                                                const int* __restrict__ nmax,
                                                void* __restrict__ out_) {
    int sb = blockIdx.x;
    int stream = sb >> 13;
    int b  = (sb >> 8) & 31;
    int co = sb & 255;
    int md = flg[0];
    int n_self  = nmax[stream];
    int n_other = nmax[1 - stream];
    bool insert  = n_other > n_self;
    bool special = insert && (co == n_self);
    int obase = sb & ~255;

    const float*  sig = sa32 + (size_t)b * HWDIM;
    const float4* sg  = (const float4*)sig;

    if (!special) {
        int ci = co;
        if (insert && co > n_self) ci = co - 1;
        int src = ord[obase + ci] & 255;         // clamp: never OOB
        size_t pb = (size_t)(b * 256 + src) * HWDIM;
        if (md == 0) {
            const u16* x = stream ? (const u16*)ir_ : (const u16*)rgb_;
            const uint4* xin = (const uint4*)(x + pb);
            uint4* o = (uint4*)((u16*)out_ + (size_t)sb * HWDIM);
            for (int i = threadIdx.x; i < 392; i += 256) {
                uint4 u = xin[i];
                float4 s0 = sg[2 * i], s1 = sg[2 * i + 1];
                uint4 r;
                r.x = pack2(u.x, s0.x, s0.y);
                r.y = pack2(u.y, s0.z, s0.w);
                r.z = pack2(u.z, s1.x, s1.y);
                r.w = pack2(u.w, s1.z, s1.w);
                o[i] = r;
            }
        } else {
            const float* x = stream ? (const float*)ir_ : (const float*)rgb_;
            const float4* xin = (const float4*)(x + pb);
            float4* o = (float4*)((float*)out_ + (size_t)sb * HWDIM);
            for (int i = threadIdx.x; i < 784; i += 256) {
                float4 v = xin[i], s = sg[i];
                o[i] = make_float4(v.x * s.x, v.y * s.y, v.z * s.z, v.w * s.w);
            }
        }
    } else {
        int src_r = ord[b * 256] & 255;
        int src_i = ord[8192 + b * 256] & 255;
        size_t pr = (size_t)(b * 256 + src_r) * HWDIM;
        size_t pi = (size_t)(b * 256 + src_i) * HWDIM;
        if (md == 0) {
            const uint4* xr = (const uint4*)((const u16*)rgb_ + pr);
            const uint4* xi = (const uint4*)((const u16*)ir_  + pi);
            uint4* o = (uint4*)((u16*)out_ + (size_t)sb * HWDIM);
            for (int i = threadIdx.x; i < 392; i += 256) {
                uint4 u = xr[i], w = xi[i];
                float4 s0 = sg[2 * i], s1 = sg[2 * i + 1];
                uint4 r;
                r.x = maxpack2(u.x, w.x, s0.x, s0.y);
                r.y = maxpack2(u.y, w.y, s0.z, s0.w);
                r.z = maxpack2(u.z, w.z, s1.x, s1.y);
                r.w = maxpack2(u.w, w.w, s1.z, s1.w);
                o[i] = r;
            }
        } else {
            const float4* xr = (const float4*)((const float*)rgb_ + pr);
            const float4* xi = (const float4*)((const float*)ir_  + pi);
            float4* o = (float4*)((float*)out_ + (size_t)sb * HWDIM);
            for (int i = threadIdx.x; i < 784; i += 256) {
                float4 u = xr[i], w = xi[i], s = sg[i];
                o[i] = make_float4(fmaxf(u.x, w.x) * s.x, fmaxf(u.y, w.y) * s.y,
                                   fmaxf(u.z, w.z) * s.z, fmaxf(u.w, w.w) * s.w);
            }
        }
    }
}

extern "C" void kernel_launch(void* const* d_in, const int* in_sizes, int n_in,
                              void* d_out, int out_size, void* d_ws, size_t ws_size,
                              hipStream_t stream) {
    const void* rgb = d_in[0];
    const void* ir  = d_in[1];

    char* ws = (char*)d_ws;
    int*    flg  = (int*)   ws;              // @ 0       (4 B)
    float*  sa32 = (float*) (ws + 1024);     // @ 1024    (401408 B)
    double* sims = (double*)(ws + 402432);   // @ 402432  (131072 B)
    int*    ord  = (int*)   (ws + 533504);   // @ 533504  (65536 B)
    int*    nmx  = (int*)   (ws + 599296);   // @ 599296  (8 B)   total < 600 KB

    k_sa    <<<dim3(13, 32), 256, 0, stream>>>(rgb, ir, flg, sa32, nmx);
    k_sim   <<<4096,         256, 0, stream>>>(rgb, ir, flg, sa32, sims);
    k_sort  <<<64,           256, 0, stream>>>(sims, ord, nmx);
    k_gather<<<16384,        256, 0, stream>>>(rgb, ir, flg, sa32, ord, nmx, d_out);
}

// Round 3
// 427.936 us; speedup vs baseline: 1.0338x; 1.0050x over previous
//
#include <hip/hip_runtime.h>
#include <math.h>

// CSCR: B=32, C=256, H=W=56 (HW=3136). Output = concat(rgb_out, ir_out).
// Dual-dtype (bf16/fp32) runtime-detected. Pipeline (4 kernels):
//  k_sa     : per-(b,hw) channel mean+max both streams -> sigmoid -> sa32.
//             1-wave blocks, grid(49,32)=1568 blocks (load-balanced on 256
//             CUs), in-wave shuffle reduction over 4 channel subgroups, no
//             LDS. Dtype detect on first 1KB of rgb (per-block, L2-free).
//  k_sim    : per-(b,c) plane dot(sa,x) & sum(x^2), fp64 accum, 16 B/lane.
//  k_sort   : stable ascending rank-sort of 256 sims per (stream,b) +
//             positive count -> atomicMax into nmx.
//  k_gather : sorted-channel gather w/ insertion * sa_sig; 16 B/lane.

#define CDIM   256
#define HWDIM  3136
#define CHW    (CDIM * HWDIM)        /* 802816 */
#define PAIRS  1568                  /* HWDIM/2 */
#define QUADS  784                   /* HWDIM/4 */

typedef unsigned short u16;
typedef unsigned int   u32;

__device__ __forceinline__ float bf2f(u32 u) { return __uint_as_float(u << 16); }
__device__ __forceinline__ u16  f2bf(float f) {
    u32 x = __float_as_uint(f);
    return (u16)((x + 0x7FFFu + ((x >> 16) & 1u)) >> 16);   // RNE
}
__device__ __forceinline__ u32 pack2(u32 u, float s0, float s1) {
    float a0 = __uint_as_float(u << 16);
    float a1 = __uint_as_float(u & 0xFFFF0000u);
    u32 lo = f2bf(a0 * s0), hi = f2bf(a1 * s1);
    return lo | (hi << 16);
}
__device__ __forceinline__ u32 maxpack2(u32 u, u32 w, float s0, float s1) {
    float a0 = __uint_as_float(u << 16), a1 = __uint_as_float(u & 0xFFFF0000u);
    float b0 = __uint_as_float(w << 16), b1 = __uint_as_float(w & 0xFFFF0000u);
    u32 lo = f2bf(fmaxf(a0, b0) * s0), hi = f2bf(fmaxf(a1, b1) * s1);
    return lo | (hi << 16);
}

// ---- k_sa: grid (49, 32), block 64 (1 wave). Wave = 16 quads x 4 channel
// subgroups; in-wave shuffle reduction; lanes 0-15 write float4 results. ----
__global__ __launch_bounds__(64) void k_sa(const void* __restrict__ rgb_,
                                           const void* __restrict__ ir_,
                                           int* __restrict__ flg,
                                           float* __restrict__ sa32,
                                           int* __restrict__ nmx) {
    int lane = threadIdx.x;             // 0..63

    // -- dtype detect: 128 u32 (512 B) of rgb head. fp32 misread as bf16
    //    gives ~46% weird low-halves; genuine bf16 N(0,1) gives 0.
    int w = 0;
    {
        u32 u = ((const u32*)rgb_)[lane];
        u32 hs[2] = { u & 0xFFFFu, u >> 16 };
        #pragma unroll
        for (int k = 0; k < 2; ++k) {
            int e = (hs[k] >> 7) & 0xFF;
            float v = bf2f(hs[k]);
            if (e == 0xFF || fabsf(v) > 1e3f) w++;
        }
    }
    #pragma unroll
    for (int off = 32; off >= 1; off >>= 1) w += __shfl_xor(w, off, 64);
    int md = (w > 8) ? 1 : 0;           // 0=bf16 1=fp32 (fp32 gives ~30/128)
    if (blockIdx.x == 0 && blockIdx.y == 0 && lane == 0) {
        flg[0] = md;
        nmx[0] = 0; nmx[1] = 0;         // zero for k_sort's atomicMax
    }

    int b  = blockIdx.y;
    int g  = lane >> 4;                               // channel subgroup 0..3
    int ql = blockIdx.x * 16 + (lane & 15);           // quad index (always <784)

    double s0 = 0.0, s1 = 0.0, s2 = 0.0, s3 = 0.0;    // rgb+ir sums per pos
    float m0r = -INFINITY, m1r = -INFINITY, m2r = -INFINITY, m3r = -INFINITY;
    float m0i = -INFINITY, m1i = -INFINITY, m2i = -INFINITY, m3i = -INFINITY;

    if (md == 1) {
        const float4* R = (const float4*)rgb_ + (size_t)b * (CHW / 4) + ql;
        const float4* I = (const float4*)ir_  + (size_t)b * (CHW / 4) + ql;
        #pragma unroll 4
        for (int k = 0; k < 64; ++k) {
            size_t o = (size_t)(4 * k + g) * QUADS;
            float4 r = R[o];
            float4 i = I[o];
            s0 += (double)r.x + (double)i.x;
            s1 += (double)r.y + (double)i.y;
            s2 += (double)r.z + (double)i.z;
            s3 += (double)r.w + (double)i.w;
            m0r = fmaxf(m0r, r.x); m1r = fmaxf(m1r, r.y);
            m2r = fmaxf(m2r, r.z); m3r = fmaxf(m3r, r.w);
            m0i = fmaxf(m0i, i.x); m1i = fmaxf(m1i, i.y);
            m2i = fmaxf(m2i, i.z); m3i = fmaxf(m3i, i.w);
        }
    } else {
        // quad = 4 bf16 = 8 B = one uint2; same quad indexing as fp32 path
        const uint2* R = (const uint2*)rgb_ + (size_t)b * (CHW / 4) + ql;
        const uint2* I = (const uint2*)ir_  + (size_t)b * (CHW / 4) + ql;
        #pragma unroll 4
        for (int k = 0; k < 64; ++k) {
            size_t o = (size_t)(4 * k + g) * QUADS;
            uint2 ur = R[o];
            uint2 ui = I[o];
            float r0 = bf2f(ur.x & 0xFFFFu), r1 = bf2f(ur.x >> 16);
            float r2 = bf2f(ur.y & 0xFFFFu), r3 = bf2f(ur.y >> 16);
            float i0 = bf2f(ui.x & 0xFFFFu), i1 = bf2f(ui.x >> 16);
            float i2 = bf2f(ui.y & 0xFFFFu), i3 = bf2f(ui.y >> 16);
            s0 += (double)r0 + (double)i0;
            s1 += (double)r1 + (double)i1;
            s2 += (double)r2 + (double)i2;
            s3 += (double)r3 + (double)i3;
            m0r = fmaxf(m0r, r0); m1r = fmaxf(m1r, r1);
            m2r = fmaxf(m2r, r2); m3r = fmaxf(m3r, r3);
            m0i = fmaxf(m0i, i0); m1i = fmaxf(m1i, i1);
            m2i = fmaxf(m2i, i2); m3i = fmaxf(m3i, i3);
        }
    }

    // -- in-wave reduction over the 4 channel subgroups (lanes xor 16, 32) --
    #pragma unroll
    for (int off = 16; off <= 32; off <<= 1) {
        s0 += __shfl_xor(s0, off, 64);
        s1 += __shfl_xor(s1, off, 64);
        s2 += __shfl_xor(s2, off, 64);
        s3 += __shfl_xor(s3, off, 64);
        m0r = fmaxf(m0r, __shfl_xor(m0r, off, 64));
        m1r = fmaxf(m1r, __shfl_xor(m1r, off, 64));
        m2r = fmaxf(m2r, __shfl_xor(m2r, off, 64));
        m3r = fmaxf(m3r, __shfl_xor(m3r, off, 64));
        m0i = fmaxf(m0i, __shfl_xor(m0i, off, 64));
        m1i = fmaxf(m1i, __shfl_xor(m1i, off, 64));
        m2i = fmaxf(m2i, __shfl_xor(m2i, off, 64));
        m3i = fmaxf(m3i, __shfl_xor(m3i, off, 64));
    }

    if (lane < 16) {
        double sa0 = fmax(s0 * (1.0 / 256.0), (double)m0r + (double)m0i);
        double sa1 = fmax(s1 * (1.0 / 256.0), (double)m1r + (double)m1i);
        double sa2 = fmax(s2 * (1.0 / 256.0), (double)m2r + (double)m2i);
        double sa3 = fmax(s3 * (1.0 / 256.0), (double)m3r + (double)m3i);
        float4 ov;
        ov.x = (float)(1.0 / (1.0 + exp(-sa0)));
        ov.y = (float)(1.0 / (1.0 + exp(-sa1)));
        ov.z = (float)(1.0 / (1.0 + exp(-sa2)));
        ov.w = (float)(1.0 / (1.0 + exp(-sa3)));
        *(float4*)&sa32[(size_t)b * HWDIM + 4 * (size_t)ql] = ov;
    }
}

// ---- k_sim: 4 planes/block (same batch), sa staged in LDS (12.25 KB) ----
__global__ __launch_bounds__(256) void k_sim(const void* __restrict__ rgb_,
                                             const void* __restrict__ ir_,
                                             const int* __restrict__ flg,
                                             const float* __restrict__ sa32,
                                             double* __restrict__ sims) {
    __shared__ float s_sa[HWDIM];
    int p0 = blockIdx.x * 4;
    int b  = (p0 >> 8) & 31;
    {
        const float4* src = (const float4*)(sa32 + (size_t)b * HWDIM);
        float4* dst = (float4*)s_sa;
        for (int i = threadIdx.x; i < QUADS; i += 256) dst[i] = src[i];
    }
    __syncthreads();

    int wid = threadIdx.x >> 6, lane = threadIdx.x & 63;
    int p = p0 + wid;
    int stream = p >> 13;
    int md = flg[0];
    int plane = p & 8191;                 // b*256 + c
    const float4* sv = (const float4*)s_sa;

    double ss = 0.0, dot = 0.0;
    if (md == 1) {
        const float4* x = (const float4*)(stream ? ir_ : rgb_) + (size_t)plane * QUADS;
        #pragma unroll 2
        for (int j = lane; j < QUADS; j += 64) {
            float4 v = x[j];
            float4 s = sv[j];
            ss  = fma((double)v.x, (double)v.x,
                  fma((double)v.y, (double)v.y,
                  fma((double)v.z, (double)v.z,
                  fma((double)v.w, (double)v.w, ss))));
            dot = fma((double)s.x, (double)v.x,
                  fma((double)s.y, (double)v.y,
                  fma((double)s.z, (double)v.z,
                  fma((double)s.w, (double)v.w, dot))));
        }
    } else {
        const u32* x = (const u32*)(stream ? ir_ : rgb_) + (size_t)plane * PAIRS;
        #pragma unroll 2
        for (int j = lane; j < QUADS; j += 64) {
            u32 w0 = x[2 * j], w1 = x[2 * j + 1];
            double v0 = (double)bf2f(w0 & 0xFFFFu), v1 = (double)bf2f(w0 >> 16);
            double v2 = (double)bf2f(w1 & 0xFFFFu), v3 = (double)bf2f(w1 >> 16);
            float4 s = sv[j];
            ss  = fma(v0, v0, fma(v1, v1, fma(v2, v2, fma(v3, v3, ss))));
            dot = fma((double)s.x, v0, fma((double)s.y, v1,
                  fma((double)s.z, v2, fma((double)s.w, v3, dot))));
        }
    }
    #pragma unroll
    for (int off = 32; off >= 1; off >>= 1) {
        ss  += __shfl_xor(ss,  off, 64);
        dot += __shfl_xor(dot, off, 64);
    }
    if (lane == 0) {
        double nrm = sqrt(ss);
        if (nrm < 1e-12) nrm = 1e-12;
        sims[p] = dot / nrm;
    }
}

// ---- k_sort: stable ascending argsort + positive count -> atomicMax nmx ----
__global__ __launch_bounds__(256) void k_sort(const double* __restrict__ sims,
                                              int* __restrict__ ord,
                                              int* __restrict__ nmx) {
    __shared__ double s[256];
    __shared__ int csum;
    int sb = blockIdx.x;
    int c  = threadIdx.x;
    double v = sims[sb * 256 + c];
    if (isnan(v)) v = -INFINITY;        // keep ranks a permutation, always
    s[c] = v;
    if (c == 0) csum = 0;
    __syncthreads();
    int rank = 0;
    #pragma unroll 8
    for (int j = 0; j < 256; ++j) {
        double u = s[j];
        rank += (u < v) || (u == v && j < c);
    }
    ord[sb * 256 + rank] = c;
    unsigned long long m = __ballot(v > 0.0);
    if ((c & 63) == 0) atomicAdd(&csum, (int)__popcll(m));
    __syncthreads();
    if (c == 0) atomicMax(&nmx[sb >> 5], csum);   // nmx pre-zeroed by k_sa
}

// ---- k_gather: grid 16384 = stream*8192 + b*256 + c_out, block 256 ----
__global__ __launch_bounds__(256) void k_gather(const void* __restrict__ rgb_,
                                                const void* __restrict__ ir_,
                                                const int* __restrict__ flg,
                                                const float* __restrict__ sa32,
                                                const int* __restrict__ ord,
                                                const int* __restrict__ nmax,
                                                void* __restrict__ out_) {
    int sb = blockIdx.x;
    int stream = sb >> 13;
    int b  = (sb >> 8) & 31;
    int co = sb & 255;
    int md = flg[0];
    int n_self  = nmax[stream];
    int n_other = nmax[1 - stream];
    bool insert  = n_other > n_self;
    bool special = insert && (co == n_self);
    int obase = sb & ~255;

    const float*  sig = sa32 + (size_t)b * HWDIM;
    const float4* sg  = (const float4*)sig;

    if (!special) {
        int ci = co;
        if (insert && co > n_self) ci = co - 1;
        int src = ord[obase + ci] & 255;         // clamp: never OOB
        size_t pb = (size_t)(b * 256 + src) * HWDIM;
        if (md == 0) {
            const u16* x = stream ? (const u16*)ir_ : (const u16*)rgb_;
            const uint4* xin = (const uint4*)(x + pb);
            uint4* o = (uint4*)((u16*)out_ + (size_t)sb * HWDIM);
            for (int i = threadIdx.x; i < 392; i += 256) {
                uint4 u = xin[i];
                float4 s0 = sg[2 * i], s1 = sg[2 * i + 1];
                uint4 r;
                r.x = pack2(u.x, s0.x, s0.y);
                r.y = pack2(u.y, s0.z, s0.w);
                r.z = pack2(u.z, s1.x, s1.y);
                r.w = pack2(u.w, s1.z, s1.w);
                o[i] = r;
            }
        } else {
            const float* x = stream ? (const float*)ir_ : (const float*)rgb_;
            const float4* xin = (const float4*)(x + pb);
            float4* o = (float4*)((float*)out_ + (size_t)sb * HWDIM);
            for (int i = threadIdx.x; i < 784; i += 256) {
                float4 v = xin[i], s = sg[i];
                o[i] = make_float4(v.x * s.x, v.y * s.y, v.z * s.z, v.w * s.w);
            }
        }
    } else {
        int src_r = ord[b * 256] & 255;
        int src_i = ord[8192 + b * 256] & 255;
        size_t pr = (size_t)(b * 256 + src_r) * HWDIM;
        size_t pi = (size_t)(b * 256 + src_i) * HWDIM;
        if (md == 0) {
            const uint4* xr = (const uint4*)((const u16*)rgb_ + pr);
            const uint4* xi = (const uint4*)((const u16*)ir_  + pi);
            uint4* o = (uint4*)((u16*)out_ + (size_t)sb * HWDIM);
            for (int i = threadIdx.x; i < 392; i += 256) {
                uint4 u = xr[i], w = xi[i];
                float4 s0 = sg[2 * i], s1 = sg[2 * i + 1];
                uint4 r;
                r.x = maxpack2(u.x, w.x, s0.x, s0.y);
                r.y = maxpack2(u.y, w.y, s0.z, s0.w);
                r.z = maxpack2(u.z, w.z, s1.x, s1.y);
                r.w = maxpack2(u.w, w.w, s1.z, s1.w);
                o[i] = r;
            }
        } else {
            const float4* xr = (const float4*)((const float*)rgb_ + pr);
            const float4* xi = (const float4*)((const float*)ir_  + pi);
            float4* o = (float4*)((float*)out_ + (size_t)sb * HWDIM);
            for (int i = threadIdx.x; i < 784; i += 256) {
                float4 u = xr[i], w = xi[i], s = sg[i];
                o[i] = make_float4(fmaxf(u.x, w.x) * s.x, fmaxf(u.y, w.y) * s.y,
                                   fmaxf(u.z, w.z) * s.z, fmaxf(u.w, w.w) * s.w);
            }
        }
    }
}

extern "C" void kernel_launch(void* const* d_in, const int* in_sizes, int n_in,
                              void* d_out, int out_size, void* d_ws, size_t ws_size,
                              hipStream_t stream) {
    const void* rgb = d_in[0];
    const void* ir  = d_in[1];

    char* ws = (char*)d_ws;
    int*    flg  = (int*)   ws;              // @ 0       (4 B)
    float*  sa32 = (float*) (ws + 1024);     // @ 1024    (401408 B)
    double* sims = (double*)(ws + 402432);   // @ 402432  (131072 B)
    int*    ord  = (int*)   (ws + 533504);   // @ 533504  (65536 B)
    int*    nmx  = (int*)   (ws + 599296);   // @ 599296  (8 B)   total < 600 KB

    k_sa    <<<dim3(49, 32), 64, 0, stream>>>(rgb, ir, flg, sa32, nmx);
    k_sim   <<<4096,        256, 0, stream>>>(rgb, ir, flg, sa32, sims);
    k_sort  <<<64,          256, 0, stream>>>(sims, ord, nmx);
    k_gather<<<16384,       256, 0, stream>>>(rgb, ir, flg, sa32, ord, nmx, d_out);
}